// Round 3
// baseline (122.722 us; speedup 1.0000x reference)
//
#include <hip/hip_runtime.h>
#include <math.h>

// MinibatchDiscrimination: B=512, IN=512, OUT=100, K=5
//   M = x @ T.view(512,500)                                  [512,500]
//   out[j,o] = sum_i exp(-sum_k |M[i,o,k]-M[j,o,k]|) - 1     [512,100]
//
// Pipeline (3 dispatches):
//  memset  : M8[512][800] = 0                     (1.6 MB, ~0.3us)
//  k1 gemm : K-split x8, 64x64 tiles, 4x4 micro, 4k-unrolled ds_read_b128,
//            unsafeAtomicAdd epilogue into padded M8[b][o*8+k]  (512 blocks)
//  k2 pair : per (o, 32-j chunk) block, LDS-staged i-loop        (1600 blocks)

#define NB    512
#define NIN   512
#define NOUT  100
#define KDIM  5
#define NCOL  (NOUT*KDIM)       // 500
#define KZ    8                 // K-split factor
#define M8_LD 800               // padded row stride of M8 (8 floats per o)

// ---------------- Kernel 1: partial GEMM, 64x64 tile, K=64/block, atomic epi
__global__ __launch_bounds__(256) void gemm_kernel(const float* __restrict__ A,
                                                   const float* __restrict__ Bm,
                                                   float* __restrict__ M8) {
    // stride 68 words: float4 rows stay 16B-aligned (68*4 % 16 == 0)
    __shared__ float As[64][68];
    __shared__ float Bs[64][68];

    const int tx = threadIdx.x;            // 0..15 (n)
    const int ty = threadIdx.y;            // 0..15 (m)
    const int tid = ty * 16 + tx;
    const int bn = blockIdx.x * 64;        // n-tile
    const int bm = blockIdx.y * 64;        // m-tile
    const int kt = blockIdx.z * 64;        // k-chunk

    // stage A tile: 64 rows x 64 k (1024 float4, coalesced)
    #pragma unroll
    for (int l = 0; l < 4; ++l) {
        int idx = tid + l * 256;
        int row = idx >> 4, q = idx & 15;
        float4 v = *reinterpret_cast<const float4*>(&A[(bm + row) * NIN + kt + q * 4]);
        *reinterpret_cast<float4*>(&As[row][q * 4]) = v;
    }
    // stage B tile: 64 k-rows x 64 n (guarded at col>=500)
    #pragma unroll
    for (int l = 0; l < 4; ++l) {
        int idx = tid + l * 256;
        int row = idx >> 4, q = idx & 15;
        int col = bn + q * 4;
        float4 v;
        if (col + 3 < NCOL) {
            v = *reinterpret_cast<const float4*>(&Bm[(kt + row) * NCOL + col]);
        } else {
            v.x = (col + 0 < NCOL) ? Bm[(kt + row) * NCOL + col + 0] : 0.f;
            v.y = (col + 1 < NCOL) ? Bm[(kt + row) * NCOL + col + 1] : 0.f;
            v.z = (col + 2 < NCOL) ? Bm[(kt + row) * NCOL + col + 2] : 0.f;
            v.w = (col + 3 < NCOL) ? Bm[(kt + row) * NCOL + col + 3] : 0.f;
        }
        *reinterpret_cast<float4*>(&Bs[row][q * 4]) = v;
    }
    __syncthreads();

    float acc[4][4];
    #pragma unroll
    for (int i = 0; i < 4; ++i)
        #pragma unroll
        for (int j = 0; j < 4; ++j) acc[i][j] = 0.f;

    // 4-k-unrolled inner loop: all LDS reads are ds_read_b128
    #pragma unroll 4
    for (int k = 0; k < 64; k += 4) {
        float4 a4[4], b4[4];
        #pragma unroll
        for (int i = 0; i < 4; ++i)
            a4[i] = *reinterpret_cast<const float4*>(&As[ty * 4 + i][k]);   // A[m_i][k..k+3]
        #pragma unroll
        for (int kk = 0; kk < 4; ++kk)
            b4[kk] = *reinterpret_cast<const float4*>(&Bs[k + kk][tx * 4]); // B[k+kk][n..n+3]
        #pragma unroll
        for (int kk = 0; kk < 4; ++kk) {
            const float* bp = reinterpret_cast<const float*>(&b4[kk]);
            #pragma unroll
            for (int i = 0; i < 4; ++i) {
                const float a = reinterpret_cast<const float*>(&a4[i])[kk];
                #pragma unroll
                for (int j = 0; j < 4; ++j) acc[i][j] += a * bp[j];
            }
        }
    }

    // epilogue: atomic-add partials into padded M8[row][o*8+kk]
    #pragma unroll
    for (int i = 0; i < 4; ++i) {
        const int row = bm + ty * 4 + i;
        #pragma unroll
        for (int j = 0; j < 4; ++j) {
            const int col = bn + tx * 4 + j;
            if (col < NCOL) {
                const int o  = col / KDIM;
                const int kk = col - o * KDIM;
                unsafeAtomicAdd(&M8[row * M8_LD + o * 8 + kk], acc[i][j]);
            }
        }
    }
}

// ---------------- Kernel 2: pairwise L1 + exp + reduce over i
// grid (100, 16): block = (o, 32 j's). 256 threads = 32 j x 8 i-splits (64 i each).
__global__ __launch_bounds__(256) void pairwise_kernel(const float* __restrict__ M8,
                                                       float* __restrict__ out) {
    __shared__ float Ms[NB * 8];      // 16 KiB
    __shared__ float partial[256];

    const int o   = blockIdx.x;       // 0..99
    const int jc  = blockIdx.y;       // 0..15
    const int tid = threadIdx.x;      // 0..255

    // stage M8[:, o*8 .. o*8+7] -> Ms; lane pairs read the two float4s of a row
    {
        const int half = tid & 1;
        for (int b = tid >> 1; b < NB; b += 128) {
            const float* src = M8 + b * M8_LD + o * 8 + half * 4;
            *reinterpret_cast<float4*>(&Ms[b * 8 + half * 4]) =
                *reinterpret_cast<const float4*>(src);
        }
    }
    __syncthreads();

    const int j  = jc * 32 + (tid & 31);
    const int i0 = (tid >> 5) * 64;

    const float4 jv = *reinterpret_cast<const float4*>(&Ms[j * 8]);
    const float  j4 = Ms[j * 8 + 4];

    float acc = 0.0f;
    #pragma unroll 8
    for (int i = i0; i < i0 + 64; ++i) {
        float4 v = *reinterpret_cast<const float4*>(&Ms[i * 8]);
        float v4 = Ms[i * 8 + 4];
        float norm = fabsf(v.x - jv.x) + fabsf(v.y - jv.y) + fabsf(v.z - jv.z)
                   + fabsf(v.w - jv.w) + fabsf(v4 - j4);
        acc += __expf(-norm);
    }

    partial[tid] = acc;
    __syncthreads();

    if (tid < 32) {
        float tot = -1.0f;            // remove exp(0) self-term
        #pragma unroll
        for (int s = 0; s < 8; ++s) tot += partial[tid + s * 32];
        out[(jc * 32 + tid) * NOUT + o] = tot;
    }
}

extern "C" void kernel_launch(void* const* d_in, const int* in_sizes, int n_in,
                              void* d_out, int out_size, void* d_ws, size_t ws_size,
                              hipStream_t stream) {
    const float* x = (const float*)d_in[0];   // [512,512]
    const float* T = (const float*)d_in[1];   // [512,500]
    float* M8  = (float*)d_ws;                // 512*800*4 = 1.6 MB
    float* out = (float*)d_out;               // [512,100]

    hipMemsetAsync(M8, 0, NB * M8_LD * sizeof(float), stream);
    gemm_kernel<<<dim3(8, 8, KZ), dim3(16, 16), 0, stream>>>(x, T, M8);
    pairwise_kernel<<<dim3(NOUT, 16), 256, 0, stream>>>(M8, out);
}

// Round 4
// 82.856 us; speedup vs baseline: 1.4812x; 1.4812x over previous
//
#include <hip/hip_runtime.h>
#include <math.h>

// MinibatchDiscrimination: B=512, IN=512, OUT=100, K=5
//   M = x @ T.view(512,500)                                  [512,500]
//   out[j,o] = sum_i exp(-sum_k |M[i,o,k]-M[j,o,k]|) - 1     [512,100]
//
// Pipeline (3 dispatches, no atomics — R3 showed cross-XCD fp32 atomics
// write-through at ~52MB and serialize; 54us vs <10us expected):
//  k1 gemm   : K-split x8, 64x64 tiles, 4x4 micro, b128 LDS reads
//              -> Mpart[8][512][500]                          (512 blocks)
//  k2 reduce : float4-vectorized sum of 8 partials -> M8[512][800]
//              (padded layout M8[b][o*8+k])                   (250 blocks)
//  k3 pair   : per (o, 32-j chunk) block, LDS-staged i-loop   (1600 blocks)

#define NB    512
#define NIN   512
#define NOUT  100
#define KDIM  5
#define NCOL  (NOUT*KDIM)       // 500
#define KZ    8                 // K-split factor
#define MP_ELEMS (NB*NCOL)      // 256000 per partial
#define M8_LD 800               // padded row stride of M8 (8 floats per o)

// ---------------- Kernel 1: partial GEMM, 64x64 tile, K=64 per block
__global__ __launch_bounds__(256) void gemm_kernel(const float* __restrict__ A,
                                                   const float* __restrict__ Bm,
                                                   float* __restrict__ Mpart) {
    // stride 68 words: float4 rows stay 16B-aligned (68*4 % 16 == 0)
    __shared__ float As[64][68];
    __shared__ float Bs[64][68];

    const int tx = threadIdx.x;            // 0..15 (n)
    const int ty = threadIdx.y;            // 0..15 (m)
    const int tid = ty * 16 + tx;
    const int bn = blockIdx.x * 64;        // n-tile
    const int bm = blockIdx.y * 64;        // m-tile
    const int kz = blockIdx.z;             // 0..7
    const int kt = kz * 64;                // k-chunk

    // stage A tile: 64 rows x 64 k (1024 float4, coalesced)
    #pragma unroll
    for (int l = 0; l < 4; ++l) {
        int idx = tid + l * 256;
        int row = idx >> 4, q = idx & 15;
        float4 v = *reinterpret_cast<const float4*>(&A[(bm + row) * NIN + kt + q * 4]);
        *reinterpret_cast<float4*>(&As[row][q * 4]) = v;
    }
    // stage B tile: 64 k-rows x 64 n (guarded at col>=500)
    #pragma unroll
    for (int l = 0; l < 4; ++l) {
        int idx = tid + l * 256;
        int row = idx >> 4, q = idx & 15;
        int col = bn + q * 4;
        float4 v;
        if (col + 3 < NCOL) {
            v = *reinterpret_cast<const float4*>(&Bm[(kt + row) * NCOL + col]);
        } else {
            v.x = (col + 0 < NCOL) ? Bm[(kt + row) * NCOL + col + 0] : 0.f;
            v.y = (col + 1 < NCOL) ? Bm[(kt + row) * NCOL + col + 1] : 0.f;
            v.z = (col + 2 < NCOL) ? Bm[(kt + row) * NCOL + col + 2] : 0.f;
            v.w = (col + 3 < NCOL) ? Bm[(kt + row) * NCOL + col + 3] : 0.f;
        }
        *reinterpret_cast<float4*>(&Bs[row][q * 4]) = v;
    }
    __syncthreads();

    float acc[4][4];
    #pragma unroll
    for (int i = 0; i < 4; ++i)
        #pragma unroll
        for (int j = 0; j < 4; ++j) acc[i][j] = 0.f;

    // 4-k-unrolled inner loop: all LDS reads are ds_read_b128
    #pragma unroll 4
    for (int k = 0; k < 64; k += 4) {
        float4 a4[4], b4[4];
        #pragma unroll
        for (int i = 0; i < 4; ++i)
            a4[i] = *reinterpret_cast<const float4*>(&As[ty * 4 + i][k]);   // A[m_i][k..k+3]
        #pragma unroll
        for (int kk = 0; kk < 4; ++kk)
            b4[kk] = *reinterpret_cast<const float4*>(&Bs[k + kk][tx * 4]); // B[k+kk][n..n+3]
        #pragma unroll
        for (int kk = 0; kk < 4; ++kk) {
            const float* bp = reinterpret_cast<const float*>(&b4[kk]);
            #pragma unroll
            for (int i = 0; i < 4; ++i) {
                const float a = reinterpret_cast<const float*>(&a4[i])[kk];
                #pragma unroll
                for (int j = 0; j < 4; ++j) acc[i][j] += a * bp[j];
            }
        }
    }

    // epilogue: plain coalesced stores into this kz's partial buffer
    float* C = Mpart + kz * MP_ELEMS;
    #pragma unroll
    for (int i = 0; i < 4; ++i) {
        const int row = bm + ty * 4 + i;
        const int col0 = bn + tx * 4;
        if (col0 + 3 < NCOL) {
            float4 v = make_float4(acc[i][0], acc[i][1], acc[i][2], acc[i][3]);
            *reinterpret_cast<float4*>(&C[row * NCOL + col0]) = v;
        } else {
            #pragma unroll
            for (int j = 0; j < 4; ++j)
                if (col0 + j < NCOL) C[row * NCOL + col0 + j] = acc[i][j];
        }
    }
}

// ---------------- Kernel 2: sum KZ partials -> M8[512][800] (M8[b][o*8+k])
// One float4 per thread: 500 = 4*125, so a float4 never straddles a row.
__global__ __launch_bounds__(256) void reduce_kernel(const float* __restrict__ Mpart,
                                                     float* __restrict__ M8) {
    const unsigned n = blockIdx.x * 256 + threadIdx.x;    // 0..63999 float4 idx
    const float4* P = reinterpret_cast<const float4*>(Mpart);
    float4 s = P[n];
    #pragma unroll
    for (int z = 1; z < KZ; ++z) {
        float4 v = P[z * (MP_ELEMS / 4) + n];
        s.x += v.x; s.y += v.y; s.z += v.z; s.w += v.w;
    }
    const unsigned b  = n / 125;           // row
    const unsigned c  = (n - b * 125) * 4; // col of element 0
    const float sv[4] = {s.x, s.y, s.z, s.w};
    #pragma unroll
    for (int e = 0; e < 4; ++e) {
        const unsigned col = c + e;
        const unsigned o   = col / KDIM;
        const unsigned kk  = col - o * KDIM;
        M8[b * M8_LD + o * 8 + kk] = sv[e];
    }
}

// ---------------- Kernel 3: pairwise L1 + exp + reduce over i
// grid (100, 16): block = (o, 32 j's). 256 threads = 32 j x 8 i-splits (64 i each).
__global__ __launch_bounds__(256) void pairwise_kernel(const float* __restrict__ M8,
                                                       float* __restrict__ out) {
    __shared__ float Ms[NB * 8];      // 16 KiB
    __shared__ float partial[256];

    const int o   = blockIdx.x;       // 0..99
    const int jc  = blockIdx.y;       // 0..15
    const int tid = threadIdx.x;      // 0..255

    // stage M8[:, o*8 .. o*8+7] -> Ms; lane pairs read the two float4s of a row
    {
        const int half = tid & 1;
        for (int b = tid >> 1; b < NB; b += 128) {
            const float* src = M8 + b * M8_LD + o * 8 + half * 4;
            *reinterpret_cast<float4*>(&Ms[b * 8 + half * 4]) =
                *reinterpret_cast<const float4*>(src);
        }
    }
    __syncthreads();

    const int j  = jc * 32 + (tid & 31);
    const int i0 = (tid >> 5) * 64;

    const float4 jv = *reinterpret_cast<const float4*>(&Ms[j * 8]);
    const float  j4 = Ms[j * 8 + 4];

    float acc = 0.0f;
    #pragma unroll 8
    for (int i = i0; i < i0 + 64; ++i) {
        float4 v = *reinterpret_cast<const float4*>(&Ms[i * 8]);
        float v4 = Ms[i * 8 + 4];
        float norm = fabsf(v.x - jv.x) + fabsf(v.y - jv.y) + fabsf(v.z - jv.z)
                   + fabsf(v.w - jv.w) + fabsf(v4 - j4);
        acc += __expf(-norm);
    }

    partial[tid] = acc;
    __syncthreads();

    if (tid < 32) {
        float tot = -1.0f;            // remove exp(0) self-term
        #pragma unroll
        for (int s = 0; s < 8; ++s) tot += partial[tid + s * 32];
        out[(jc * 32 + tid) * NOUT + o] = tot;
    }
}

extern "C" void kernel_launch(void* const* d_in, const int* in_sizes, int n_in,
                              void* d_out, int out_size, void* d_ws, size_t ws_size,
                              hipStream_t stream) {
    const float* x = (const float*)d_in[0];   // [512,512]
    const float* T = (const float*)d_in[1];   // [512,500]
    float* Mpart = (float*)d_ws;                          // 8 * 1.024 MB
    float* M8    = (float*)d_ws + KZ * MP_ELEMS;          // 512*800*4 = 1.6 MB
    float* out   = (float*)d_out;                         // [512,100]

    gemm_kernel<<<dim3(8, 8, KZ), dim3(16, 16), 0, stream>>>(x, T, Mpart);
    reduce_kernel<<<250, 256, 0, stream>>>(Mpart, M8);
    pairwise_kernel<<<dim3(NOUT, 16), 256, 0, stream>>>(M8, out);
}